// Round 1
// baseline (4945.602 us; speedup 1.0000x reference)
//
#include <hip/hip_runtime.h>

#define NN 10000    // nodes
#define RR 100      // relations
#define EE 5000     // edges per relation
#define D0 2048
#define D1 128
#define D2 64
#define D3 20

// ---------------------------------------------------------------------------
// gemm0: x[NN,D1] += x_drug[NN,D0] @ drug_w[D0,D1]   (K-split over blockIdx.y)
// tile 64 rows x 128 cols, K-chunk 16, thread = 8 rows x 4 cols
// ---------------------------------------------------------------------------
__global__ __launch_bounds__(256) void gemm0_kernel(
    const float* __restrict__ A, const float* __restrict__ B,
    float* __restrict__ C) {
  __shared__ __align__(16) float As[16][68];   // [k][row], stride 68 (272B, 16B-mult)
  __shared__ __align__(16) float Bs[16][128];  // [k][col]
  const int tid = threadIdx.x;
  const int tx = tid & 31, ty = tid >> 5;
  const int m0 = blockIdx.x * 64;
  const int kbase0 = blockIdx.y * 512;

  float acc[8][4];
#pragma unroll
  for (int i = 0; i < 8; i++)
#pragma unroll
    for (int j = 0; j < 4; j++) acc[i][j] = 0.f;

  const int lrow = tid >> 2, lq = tid & 3;
  int grow = m0 + lrow;
  if (grow >= NN) grow = NN - 1;

  for (int kc = 0; kc < 32; kc++) {
    const int kb = kbase0 + kc * 16;
    __syncthreads();
    {
      float4 av = *(const float4*)&A[(size_t)grow * D0 + kb + lq * 4];
      As[lq * 4 + 0][lrow] = av.x;
      As[lq * 4 + 1][lrow] = av.y;
      As[lq * 4 + 2][lrow] = av.z;
      As[lq * 4 + 3][lrow] = av.w;
    }
#pragma unroll
    for (int p = 0; p < 2; p++) {
      int idx = p * 256 + tid;
      int br = idx >> 5, bc = idx & 31;
      *(float4*)&Bs[br][bc * 4] = *(const float4*)&B[(size_t)(kb + br) * D1 + bc * 4];
    }
    __syncthreads();
#pragma unroll
    for (int k = 0; k < 16; k++) {
      float4 a0 = *(const float4*)&As[k][ty * 8];
      float4 a1 = *(const float4*)&As[k][ty * 8 + 4];
      float4 bv = *(const float4*)&Bs[k][tx * 4];
      float ar[8] = {a0.x, a0.y, a0.z, a0.w, a1.x, a1.y, a1.z, a1.w};
      float br_[4] = {bv.x, bv.y, bv.z, bv.w};
#pragma unroll
      for (int i = 0; i < 8; i++)
#pragma unroll
        for (int j = 0; j < 4; j++) acc[i][j] += ar[i] * br_[j];
    }
  }
#pragma unroll
  for (int i = 0; i < 8; i++) {
    int row = m0 + ty * 8 + i;
    if (row < NN) {
#pragma unroll
      for (int j = 0; j < 4; j++)
        atomicAdd(&C[(size_t)row * D1 + tx * 4 + j], acc[i][j]);
    }
  }
}

// ---------------------------------------------------------------------------
// deg[r*NN + dst] += 1 for every edge (shared by both layers)
// ---------------------------------------------------------------------------
__global__ void deg_kernel(const int* __restrict__ ei, float* __restrict__ deg) {
  int gid = blockIdx.x * 256 + threadIdx.x;
  if (gid >= RR * EE) return;
  int r = gid / EE, e = gid - r * EE;
  int d = ei[r * 2 * EE + EE + e];
  atomicAdd(&deg[r * NN + d], 1.0f);
}

// ---------------------------------------------------------------------------
// W[r] = sum_b comp[r,b] * basis[b]   (io = IN*OUT elements per relation)
// ---------------------------------------------------------------------------
__global__ void wmix_kernel(const float* __restrict__ comp,
                            const float* __restrict__ basis,
                            float* __restrict__ W, int io) {
  int r = blockIdx.x;
  __shared__ float c[8];
  if (threadIdx.x < 8) c[threadIdx.x] = comp[r * 8 + threadIdx.x];
  __syncthreads();
  for (int idx = threadIdx.x; idx < io; idx += blockDim.x) {
    float s = 0.f;
#pragma unroll
    for (int b = 0; b < 8; b++) s += c[b] * basis[b * io + idx];
    W[r * io + idx] = s;
  }
}

// ---------------------------------------------------------------------------
// msg1: for relation r, chunk of 64 edges:
//   agg1[dst, :64] += (x[src, :128] @ W1[r]) / max(deg[r,dst],1)
// tile 64 edges x 64 outs, K=128 in chunks of 16, thread = 4 edges x 4 outs
// ---------------------------------------------------------------------------
__global__ __launch_bounds__(256) void msg1_kernel(
    const float* __restrict__ x, const float* __restrict__ W1,
    const float* __restrict__ deg, const int* __restrict__ ei,
    float* __restrict__ agg) {
  const int r = blockIdx.y;
  const int ec = blockIdx.x * 64;
  __shared__ __align__(16) float Xs[16][68];  // [k][edge]
  __shared__ __align__(16) float Ws[16][64];  // [k][out]
  __shared__ int s_src[64], s_dst[64];
  __shared__ float s_scale[64];
  const int tid = threadIdx.x;

  if (tid < 64) {
    int ge = ec + tid;
    bool valid = ge < EE;
    int s = valid ? ei[r * 2 * EE + ge] : 0;
    int d = valid ? ei[r * 2 * EE + EE + ge] : 0;
    s_src[tid] = s;
    s_dst[tid] = d;
    s_scale[tid] = valid ? (1.0f / fmaxf(deg[r * NN + d], 1.0f)) : 0.0f;
  }
  __syncthreads();

  const int eg = tid & 15, og = tid >> 4;
  const int le = tid >> 2, lq = tid & 3;
  const int src_row = s_src[le];
  const float* Wr = W1 + (size_t)r * D1 * D2;

  float acc[4][4];
#pragma unroll
  for (int i = 0; i < 4; i++)
#pragma unroll
    for (int j = 0; j < 4; j++) acc[i][j] = 0.f;

  for (int kc = 0; kc < 8; kc++) {
    const int kb = kc * 16;
    __syncthreads();
    {
      float4 xv = *(const float4*)&x[(size_t)src_row * D1 + kb + lq * 4];
      Xs[lq * 4 + 0][le] = xv.x;
      Xs[lq * 4 + 1][le] = xv.y;
      Xs[lq * 4 + 2][le] = xv.z;
      Xs[lq * 4 + 3][le] = xv.w;
    }
    {
      int wr = tid >> 4, wc = tid & 15;
      *(float4*)&Ws[wr][wc * 4] = *(const float4*)&Wr[(size_t)(kb + wr) * D2 + wc * 4];
    }
    __syncthreads();
#pragma unroll
    for (int k = 0; k < 16; k++) {
      float4 a = *(const float4*)&Xs[k][eg * 4];
      float4 b = *(const float4*)&Ws[k][og * 4];
      float ar[4] = {a.x, a.y, a.z, a.w};
      float br_[4] = {b.x, b.y, b.z, b.w};
#pragma unroll
      for (int i = 0; i < 4; i++)
#pragma unroll
        for (int j = 0; j < 4; j++) acc[i][j] += ar[i] * br_[j];
    }
  }
#pragma unroll
  for (int i = 0; i < 4; i++) {
    int e = eg * 4 + i;
    float sc = s_scale[e];
    int d = s_dst[e];
#pragma unroll
    for (int j = 0; j < 4; j++)
      atomicAdd(&agg[(size_t)d * D2 + og * 4 + j], acc[i][j] * sc);
  }
}

// ---------------------------------------------------------------------------
// h = relu(x @ root1 + agg1 + bias1)   tile 64 rows x 64 outs, K=128
// ---------------------------------------------------------------------------
__global__ __launch_bounds__(256) void hlayer_kernel(
    const float* __restrict__ x, const float* __restrict__ root1,
    const float* __restrict__ agg1, const float* __restrict__ bias1,
    float* __restrict__ h) {
  const int m0 = blockIdx.x * 64;
  __shared__ __align__(16) float Xs[16][68];
  __shared__ __align__(16) float Ws[16][64];
  const int tid = threadIdx.x;
  const int eg = tid & 15, og = tid >> 4;
  const int le = tid >> 2, lq = tid & 3;
  int grow = m0 + le;
  if (grow >= NN) grow = NN - 1;

  float acc[4][4];
#pragma unroll
  for (int i = 0; i < 4; i++)
#pragma unroll
    for (int j = 0; j < 4; j++) acc[i][j] = 0.f;

  for (int kc = 0; kc < 8; kc++) {
    const int kb = kc * 16;
    __syncthreads();
    {
      float4 xv = *(const float4*)&x[(size_t)grow * D1 + kb + lq * 4];
      Xs[lq * 4 + 0][le] = xv.x;
      Xs[lq * 4 + 1][le] = xv.y;
      Xs[lq * 4 + 2][le] = xv.z;
      Xs[lq * 4 + 3][le] = xv.w;
    }
    {
      int wr = tid >> 4, wc = tid & 15;
      *(float4*)&Ws[wr][wc * 4] = *(const float4*)&root1[(size_t)(kb + wr) * D2 + wc * 4];
    }
    __syncthreads();
#pragma unroll
    for (int k = 0; k < 16; k++) {
      float4 a = *(const float4*)&Xs[k][eg * 4];
      float4 b = *(const float4*)&Ws[k][og * 4];
      float ar[4] = {a.x, a.y, a.z, a.w};
      float br_[4] = {b.x, b.y, b.z, b.w};
#pragma unroll
      for (int i = 0; i < 4; i++)
#pragma unroll
        for (int j = 0; j < 4; j++) acc[i][j] += ar[i] * br_[j];
    }
  }
#pragma unroll
  for (int i = 0; i < 4; i++) {
    int row = m0 + eg * 4 + i;
    if (row < NN) {
#pragma unroll
      for (int j = 0; j < 4; j++) {
        int o = og * 4 + j;
        float v = acc[i][j] + agg1[(size_t)row * D2 + o] + bias1[o];
        h[(size_t)row * D2 + o] = fmaxf(v, 0.f);
      }
    }
  }
}

// ---------------------------------------------------------------------------
// msg2: for relation r, chunk of 256 edges:
//   agg2[dst, :20] += (h[src, :64] @ W2[r]) / max(deg[r,dst],1)
// tile 256 edges x 20 outs, K=64 in chunks of 16, 320 threads,
// thread = 4 edges x 4 outs (og in 0..4 -> 20 outs)
// ---------------------------------------------------------------------------
__global__ __launch_bounds__(320) void msg2_kernel(
    const float* __restrict__ hbuf, const float* __restrict__ W2,
    const float* __restrict__ deg, const int* __restrict__ ei,
    float* __restrict__ agg) {
  const int r = blockIdx.y;
  const int ec = blockIdx.x * 256;
  __shared__ __align__(16) float Xs[16][260];  // [k][edge], stride 260 (1040B)
  __shared__ __align__(16) float Ws[16][20];   // [k][out], stride 20 (80B)
  __shared__ int s_src[256], s_dst[256];
  __shared__ float s_scale[256];
  const int tid = threadIdx.x;

  if (tid < 256) {
    int ge = ec + tid;
    bool valid = ge < EE;
    int s = valid ? ei[r * 2 * EE + ge] : 0;
    int d = valid ? ei[r * 2 * EE + EE + ge] : 0;
    s_src[tid] = s;
    s_dst[tid] = d;
    s_scale[tid] = valid ? (1.0f / fmaxf(deg[r * NN + d], 1.0f)) : 0.0f;
  }
  __syncthreads();

  const int og = tid / 64;        // 0..4
  const int eg = tid % 64;        // 0..63 (4 edges each)
  const float* Wr = W2 + (size_t)r * D2 * D3;

  float acc[4][4];
#pragma unroll
  for (int i = 0; i < 4; i++)
#pragma unroll
    for (int j = 0; j < 4; j++) acc[i][j] = 0.f;

  for (int kc = 0; kc < 4; kc++) {
    const int kb = kc * 16;
    __syncthreads();
    if (tid < 256) {
      const int q = tid & 3;
#pragma unroll
      for (int p = 0; p < 4; p++) {
        int e = p * 64 + (tid >> 2);
        float4 v = *(const float4*)&hbuf[(size_t)s_src[e] * D2 + kb + q * 4];
        Xs[q * 4 + 0][e] = v.x;
        Xs[q * 4 + 1][e] = v.y;
        Xs[q * 4 + 2][e] = v.z;
        Xs[q * 4 + 3][e] = v.w;
      }
    } else {
      int t = tid - 256;
#pragma unroll
      for (int p = 0; p < 5; p++) {
        int idx = p * 64 + t;
        int row = idx / 20, c = idx - row * 20;
        Ws[row][c] = Wr[(size_t)(kb + row) * D3 + c];
      }
    }
    __syncthreads();
#pragma unroll
    for (int k = 0; k < 16; k++) {
      float4 a = *(const float4*)&Xs[k][eg * 4];
      float4 b = *(const float4*)&Ws[k][og * 4];
      float ar[4] = {a.x, a.y, a.z, a.w};
      float br_[4] = {b.x, b.y, b.z, b.w};
#pragma unroll
      for (int i = 0; i < 4; i++)
#pragma unroll
        for (int j = 0; j < 4; j++) acc[i][j] += ar[i] * br_[j];
    }
  }
#pragma unroll
  for (int i = 0; i < 4; i++) {
    int e = eg * 4 + i;
    float sc = s_scale[e];
    int d = s_dst[e];
#pragma unroll
    for (int j = 0; j < 4; j++)
      atomicAdd(&agg[(size_t)d * D3 + og * 4 + j], acc[i][j] * sc);
  }
}

// ---------------------------------------------------------------------------
// out = h @ root2 + agg2 + bias2   tile 256 rows x 20 outs, K=64, 320 threads
// ---------------------------------------------------------------------------
__global__ __launch_bounds__(320) void out_kernel(
    const float* __restrict__ hbuf, const float* __restrict__ root2,
    const float* __restrict__ agg2, const float* __restrict__ bias2,
    float* __restrict__ out) {
  const int m0 = blockIdx.x * 256;
  __shared__ __align__(16) float Xs[16][260];
  __shared__ __align__(16) float Ws[16][20];
  const int tid = threadIdx.x;
  const int og = tid / 64;
  const int eg = tid % 64;

  float acc[4][4];
#pragma unroll
  for (int i = 0; i < 4; i++)
#pragma unroll
    for (int j = 0; j < 4; j++) acc[i][j] = 0.f;

  for (int kc = 0; kc < 4; kc++) {
    const int kb = kc * 16;
    __syncthreads();
    if (tid < 256) {
      const int q = tid & 3;
#pragma unroll
      for (int p = 0; p < 4; p++) {
        int e = p * 64 + (tid >> 2);
        int row = m0 + e;
        if (row >= NN) row = NN - 1;
        float4 v = *(const float4*)&hbuf[(size_t)row * D2 + kb + q * 4];
        Xs[q * 4 + 0][e] = v.x;
        Xs[q * 4 + 1][e] = v.y;
        Xs[q * 4 + 2][e] = v.z;
        Xs[q * 4 + 3][e] = v.w;
      }
    } else {
      int t = tid - 256;
#pragma unroll
      for (int p = 0; p < 5; p++) {
        int idx = p * 64 + t;
        int row = idx / 20, c = idx - row * 20;
        Ws[row][c] = root2[(size_t)(kb + row) * D3 + c];
      }
    }
    __syncthreads();
#pragma unroll
    for (int k = 0; k < 16; k++) {
      float4 a = *(const float4*)&Xs[k][eg * 4];
      float4 b = *(const float4*)&Ws[k][og * 4];
      float ar[4] = {a.x, a.y, a.z, a.w};
      float br_[4] = {b.x, b.y, b.z, b.w};
#pragma unroll
      for (int i = 0; i < 4; i++)
#pragma unroll
        for (int j = 0; j < 4; j++) acc[i][j] += ar[i] * br_[j];
    }
  }
#pragma unroll
  for (int i = 0; i < 4; i++) {
    int row = m0 + eg * 4 + i;
    if (row < NN) {
#pragma unroll
      for (int j = 0; j < 4; j++) {
        int o = og * 4 + j;
        out[(size_t)row * D3 + o] =
            acc[i][j] + agg2[(size_t)row * D3 + o] + bias2[o];
      }
    }
  }
}

// ---------------------------------------------------------------------------
extern "C" void kernel_launch(void* const* d_in, const int* in_sizes, int n_in,
                              void* d_out, int out_size, void* d_ws,
                              size_t ws_size, hipStream_t stream) {
  const float* x_drug = (const float*)d_in[0];
  const float* drug_w = (const float*)d_in[1];
  const int* ei       = (const int*)d_in[2];
  const float* basis1 = (const float*)d_in[3];
  const float* comp1  = (const float*)d_in[4];
  const float* root1  = (const float*)d_in[5];
  const float* bias1  = (const float*)d_in[6];
  const float* basis2 = (const float*)d_in[7];
  const float* comp2  = (const float*)d_in[8];
  const float* root2  = (const float*)d_in[9];
  const float* bias2  = (const float*)d_in[10];
  float* out = (float*)d_out;

  float* ws   = (float*)d_ws;
  float* x    = ws;                  // 10000*128   = 1,280,000
  float* W1   = x    + 1280000;      // 100*128*64  =   819,200
  float* deg  = W1   + 819200;       // 100*10000   = 1,000,000
  float* agg1 = deg  + 1000000;      // 10000*64    =   640,000
  float* h    = agg1 + 640000;       // 10000*64    =   640,000
  float* W2   = h    + 640000;       // 100*64*20   =   128,000
  float* agg2 = W2   + 128000;       // 10000*20    =   200,000

  hipMemsetAsync(x,    0, (size_t)1280000 * 4, stream);
  hipMemsetAsync(deg,  0, (size_t)1000000 * 4, stream);
  hipMemsetAsync(agg1, 0, (size_t)640000 * 4, stream);
  hipMemsetAsync(agg2, 0, (size_t)200000 * 4, stream);

  gemm0_kernel<<<dim3(157, 4), 256, 0, stream>>>(x_drug, drug_w, x);
  deg_kernel<<<(RR * EE + 255) / 256, 256, 0, stream>>>(ei, deg);
  wmix_kernel<<<RR, 256, 0, stream>>>(comp1, basis1, W1, D1 * D2);
  wmix_kernel<<<RR, 256, 0, stream>>>(comp2, basis2, W2, D2 * D3);
  msg1_kernel<<<dim3((EE + 63) / 64, RR), 256, 0, stream>>>(x, W1, deg, ei, agg1);
  hlayer_kernel<<<(NN + 63) / 64, 256, 0, stream>>>(x, root1, agg1, bias1, h);
  msg2_kernel<<<dim3((EE + 255) / 256, RR), 320, 0, stream>>>(h, W2, deg, ei, agg2);
  out_kernel<<<(NN + 255) / 256, 320, 0, stream>>>(h, root2, agg2, bias2, out);
}

// Round 2
// 567.783 us; speedup vs baseline: 8.7104x; 8.7104x over previous
//
#include <hip/hip_runtime.h>

#define NN 10000    // nodes
#define RR 100      // relations
#define EE 5000     // edges per relation
#define D0 2048
#define D1 128
#define D2 64
#define D3 20
#define NE (RR*EE)  // 500000 edges total

// ---------------------------------------------------------------------------
// gemm0: x[NN,D1] += x_drug[NN,D0] @ drug_w[D0,D1]   (K-split over blockIdx.y)
// tile 64 rows x 128 cols, K-chunk 16, thread = 8 rows x 4 cols
// ---------------------------------------------------------------------------
__global__ __launch_bounds__(256) void gemm0_kernel(
    const float* __restrict__ A, const float* __restrict__ B,
    float* __restrict__ C) {
  __shared__ __align__(16) float As[16][68];
  __shared__ __align__(16) float Bs[16][128];
  const int tid = threadIdx.x;
  const int tx = tid & 31, ty = tid >> 5;
  const int m0 = blockIdx.x * 64;
  const int kbase0 = blockIdx.y * 512;

  float acc[8][4];
#pragma unroll
  for (int i = 0; i < 8; i++)
#pragma unroll
    for (int j = 0; j < 4; j++) acc[i][j] = 0.f;

  const int lrow = tid >> 2, lq = tid & 3;
  int grow = m0 + lrow;
  if (grow >= NN) grow = NN - 1;

  for (int kc = 0; kc < 32; kc++) {
    const int kb = kbase0 + kc * 16;
    __syncthreads();
    {
      float4 av = *(const float4*)&A[(size_t)grow * D0 + kb + lq * 4];
      As[lq * 4 + 0][lrow] = av.x;
      As[lq * 4 + 1][lrow] = av.y;
      As[lq * 4 + 2][lrow] = av.z;
      As[lq * 4 + 3][lrow] = av.w;
    }
#pragma unroll
    for (int p = 0; p < 2; p++) {
      int idx = p * 256 + tid;
      int br = idx >> 5, bc = idx & 31;
      *(float4*)&Bs[br][bc * 4] = *(const float4*)&B[(size_t)(kb + br) * D1 + bc * 4];
    }
    __syncthreads();
#pragma unroll
    for (int k = 0; k < 16; k++) {
      float4 a0 = *(const float4*)&As[k][ty * 8];
      float4 a1 = *(const float4*)&As[k][ty * 8 + 4];
      float4 bv = *(const float4*)&Bs[k][tx * 4];
      float ar[8] = {a0.x, a0.y, a0.z, a0.w, a1.x, a1.y, a1.z, a1.w};
      float br_[4] = {bv.x, bv.y, bv.z, bv.w};
#pragma unroll
      for (int i = 0; i < 8; i++)
#pragma unroll
        for (int j = 0; j < 4; j++) acc[i][j] += ar[i] * br_[j];
    }
  }
#pragma unroll
  for (int i = 0; i < 8; i++) {
    int row = m0 + ty * 8 + i;
    if (row < NN) {
#pragma unroll
      for (int j = 0; j < 4; j++)
        atomicAdd(&C[(size_t)row * D1 + tx * 4 + j], acc[i][j]);
    }
  }
}

// ---------------------------------------------------------------------------
// CSR build: count edges per dst + deg per (r,dst)
// ---------------------------------------------------------------------------
__global__ void count_kernel(const int* __restrict__ ei, int* __restrict__ cnt,
                             int* __restrict__ deg) {
  int gid = blockIdx.x * 256 + threadIdx.x;
  if (gid >= NE) return;
  int r = gid / EE, e = gid - r * EE;
  int d = ei[r * 2 * EE + EE + e];
  atomicAdd(&cnt[d], 1);
  atomicAdd(&deg[r * NN + d], 1);
}

// single-block exclusive scan of cnt[NN] -> off[NN+1]; cursor = off copy
__global__ __launch_bounds__(1024) void scan_kernel(const int* __restrict__ cnt,
                                                    int* __restrict__ off,
                                                    int* __restrict__ cursor) {
  __shared__ int s[1024];
  __shared__ int carry;
  int tid = threadIdx.x;
  if (tid == 0) carry = 0;
  __syncthreads();
  for (int base = 0; base < NN; base += 1024) {
    int i = base + tid;
    int v = (i < NN) ? cnt[i] : 0;
    s[tid] = v;
    __syncthreads();
    for (int d = 1; d < 1024; d <<= 1) {
      int t = (tid >= d) ? s[tid - d] : 0;
      __syncthreads();
      s[tid] += t;
      __syncthreads();
    }
    int excl = carry + s[tid] - v;
    if (i < NN) {
      off[i] = excl;
      cursor[i] = excl;
    }
    __syncthreads();
    if (tid == 1023) carry += s[1023];
    __syncthreads();
  }
  if (tid == 0) off[NN] = carry;
}

// scatter edges into dst-sorted order; rec = (r<<14)|src, esc = 1/max(deg,1)
__global__ void scatter_kernel(const int* __restrict__ ei,
                               const int* __restrict__ deg,
                               int* __restrict__ cursor, int* __restrict__ rec,
                               float* __restrict__ esc) {
  int gid = blockIdx.x * 256 + threadIdx.x;
  if (gid >= NE) return;
  int r = gid / EE, e = gid - r * EE;
  int s = ei[r * 2 * EE + e];
  int d = ei[r * 2 * EE + EE + e];
  int p = atomicAdd(&cursor[d], 1);
  rec[p] = (r << 14) | s;
  esc[p] = 1.0f / fmaxf((float)deg[r * NN + d], 1.0f);
}

// ---------------------------------------------------------------------------
// basis transposes: Bt1[i][b*64+o] = basis1[b][i][o]  (128 x 512)
//                   Bt2[i][b*20+o] = basis2[b][i][o]  (64 x 192, cols>=160 = 0)
// ---------------------------------------------------------------------------
__global__ void t_basis1_kernel(const float* __restrict__ basis,
                                float* __restrict__ Bt) {
  int idx = blockIdx.x * 256 + threadIdx.x;
  if (idx >= 8 * 128 * 64) return;
  int b = idx >> 13, rem = idx & 8191;
  int i = rem >> 6, o = rem & 63;
  Bt[i * 512 + b * 64 + o] = basis[idx];
}

__global__ void t_basis2_kernel(const float* __restrict__ basis,
                                float* __restrict__ Bt) {
  int idx = blockIdx.x * 256 + threadIdx.x;
  if (idx >= 64 * 192) return;
  int i = idx / 192, c = idx - i * 192;
  float v = 0.f;
  if (c < 160) {
    int b = c / 20, o = c - b * 20;
    v = basis[b * 64 * 20 + i * 20 + o];
  }
  Bt[idx] = v;
}

// ---------------------------------------------------------------------------
// generic 64x64 tile GEMM: C[NN,Ncols] = A[NN,K] @ B[K,Ncols]; K%16==0, Ncols%64==0
// ---------------------------------------------------------------------------
__global__ __launch_bounds__(256) void gemm_tile_kernel(
    const float* __restrict__ A, const float* __restrict__ B,
    float* __restrict__ C, int K, int Ncols) {
  __shared__ __align__(16) float Xs[16][68];
  __shared__ __align__(16) float Ws[16][64];
  const int tid = threadIdx.x;
  const int m0 = blockIdx.x * 64;
  const int n0 = blockIdx.y * 64;
  const int eg = tid & 15, og = tid >> 4;
  const int le = tid >> 2, lq = tid & 3;
  int grow = m0 + le;
  if (grow >= NN) grow = NN - 1;

  float acc[4][4];
#pragma unroll
  for (int i = 0; i < 4; i++)
#pragma unroll
    for (int j = 0; j < 4; j++) acc[i][j] = 0.f;

  for (int kb = 0; kb < K; kb += 16) {
    __syncthreads();
    {
      float4 xv = *(const float4*)&A[(size_t)grow * K + kb + lq * 4];
      Xs[lq * 4 + 0][le] = xv.x;
      Xs[lq * 4 + 1][le] = xv.y;
      Xs[lq * 4 + 2][le] = xv.z;
      Xs[lq * 4 + 3][le] = xv.w;
    }
    {
      int wr = tid >> 4, wc = tid & 15;
      *(float4*)&Ws[wr][wc * 4] =
          *(const float4*)&B[(size_t)(kb + wr) * Ncols + n0 + wc * 4];
    }
    __syncthreads();
#pragma unroll
    for (int k = 0; k < 16; k++) {
      float4 a = *(const float4*)&Xs[k][eg * 4];
      float4 b = *(const float4*)&Ws[k][og * 4];
      float ar[4] = {a.x, a.y, a.z, a.w};
      float br_[4] = {b.x, b.y, b.z, b.w};
#pragma unroll
      for (int i = 0; i < 4; i++)
#pragma unroll
        for (int j = 0; j < 4; j++) acc[i][j] += ar[i] * br_[j];
    }
  }
#pragma unroll
  for (int i = 0; i < 4; i++) {
    int row = m0 + eg * 4 + i;
    if (row < NN) {
#pragma unroll
      for (int j = 0; j < 4; j++)
        C[(size_t)row * Ncols + n0 + og * 4 + j] = acc[i][j];
    }
  }
}

// ---------------------------------------------------------------------------
// agg1: one wave per dst node, lane = output channel (64 outs).
// agg1[n,o] = sum_{edges e->n} esc[e] * sum_b comp1[r_e,b] * U1[src_e, b*64+o]
// ---------------------------------------------------------------------------
__global__ __launch_bounds__(256) void agg1_kernel(
    const float* __restrict__ U1, const int* __restrict__ off,
    const int* __restrict__ rec, const float* __restrict__ esc,
    const float* __restrict__ comp, float* __restrict__ agg1) {
  __shared__ float s_comp[RR * 8];
  const int tid = threadIdx.x;
  for (int i = tid; i < RR * 8; i += 256) s_comp[i] = comp[i];
  __syncthreads();
  const int wave = tid >> 6, lane = tid & 63;
  const int n = blockIdx.x * 4 + wave;
  if (n >= NN) return;
  const int beg = off[n], end = off[n + 1];
  float acc = 0.f;
  int idx = beg;
  for (; idx + 1 < end; idx += 2) {
    int rc0 = rec[idx], rc1 = rec[idx + 1];
    float sc0 = esc[idx], sc1 = esc[idx + 1];
    const float* u0 = &U1[(size_t)(rc0 & 16383) * 512 + lane];
    const float* u1 = &U1[(size_t)(rc1 & 16383) * 512 + lane];
    const float* c0 = &s_comp[(rc0 >> 14) * 8];
    const float* c1 = &s_comp[(rc1 >> 14) * 8];
    float t0 = 0.f, t1 = 0.f;
#pragma unroll
    for (int b = 0; b < 8; b++) t0 += c0[b] * u0[b * 64];
#pragma unroll
    for (int b = 0; b < 8; b++) t1 += c1[b] * u1[b * 64];
    acc += sc0 * t0 + sc1 * t1;
  }
  if (idx < end) {
    int rc = rec[idx];
    float sc = esc[idx];
    const float* u = &U1[(size_t)(rc & 16383) * 512 + lane];
    const float* c = &s_comp[(rc >> 14) * 8];
    float t = 0.f;
#pragma unroll
    for (int b = 0; b < 8; b++) t += c[b] * u[b * 64];
    acc += sc * t;
  }
  agg1[(size_t)n * D2 + lane] = acc;
}

// ---------------------------------------------------------------------------
// agg2: one wave per dst node; lanes = 3 edges x 20 outs (lanes 60..63 idle).
// agg2[n,o] = sum_e esc[e] * sum_b comp2[r_e,b] * U2[src_e*192 + b*20 + o]
// ---------------------------------------------------------------------------
__global__ __launch_bounds__(256) void agg2_kernel(
    const float* __restrict__ U2, const int* __restrict__ off,
    const int* __restrict__ rec, const float* __restrict__ esc,
    const float* __restrict__ comp, float* __restrict__ agg2) {
  __shared__ float s_comp[RR * 8];
  const int tid = threadIdx.x;
  for (int i = tid; i < RR * 8; i += 256) s_comp[i] = comp[i];
  __syncthreads();
  const int wave = tid >> 6, lane = tid & 63;
  const int n = blockIdx.x * 4 + wave;
  if (n >= NN) return;
  const int j = lane / 20;            // 0..3 (j==3 idle)
  const int o = lane - j * 20;
  const bool active = lane < 60;
  const int beg = off[n], end = off[n + 1];
  float acc = 0.f;
  for (int base = beg; base < end; base += 3) {
    int idx = base + j;
    bool v = active && (idx < end);
    int idxc = v ? idx : beg;
    int rc = rec[idxc];
    float sc = v ? esc[idxc] : 0.f;
    const float* u = &U2[(size_t)(rc & 16383) * 192 + o];
    const float* c = &s_comp[(rc >> 14) * 8];
    float t = 0.f;
#pragma unroll
    for (int b = 0; b < 8; b++) t += c[b] * u[b * 20];
    acc += sc * t;
  }
  float a1 = __shfl(acc, (lane + 20) & 63, 64);
  float a2 = __shfl(acc, (lane + 40) & 63, 64);
  if (lane < 20) agg2[(size_t)n * D3 + lane] = acc + a1 + a2;
}

// ---------------------------------------------------------------------------
// h = relu(x @ root1 + agg1 + bias1)   tile 64 rows x 64 outs, K=128
// ---------------------------------------------------------------------------
__global__ __launch_bounds__(256) void hlayer_kernel(
    const float* __restrict__ x, const float* __restrict__ root1,
    const float* __restrict__ agg1, const float* __restrict__ bias1,
    float* __restrict__ h) {
  const int m0 = blockIdx.x * 64;
  __shared__ __align__(16) float Xs[16][68];
  __shared__ __align__(16) float Ws[16][64];
  const int tid = threadIdx.x;
  const int eg = tid & 15, og = tid >> 4;
  const int le = tid >> 2, lq = tid & 3;
  int grow = m0 + le;
  if (grow >= NN) grow = NN - 1;

  float acc[4][4];
#pragma unroll
  for (int i = 0; i < 4; i++)
#pragma unroll
    for (int j = 0; j < 4; j++) acc[i][j] = 0.f;

  for (int kc = 0; kc < 8; kc++) {
    const int kb = kc * 16;
    __syncthreads();
    {
      float4 xv = *(const float4*)&x[(size_t)grow * D1 + kb + lq * 4];
      Xs[lq * 4 + 0][le] = xv.x;
      Xs[lq * 4 + 1][le] = xv.y;
      Xs[lq * 4 + 2][le] = xv.z;
      Xs[lq * 4 + 3][le] = xv.w;
    }
    {
      int wr = tid >> 4, wc = tid & 15;
      *(float4*)&Ws[wr][wc * 4] =
          *(const float4*)&root1[(size_t)(kb + wr) * D2 + wc * 4];
    }
    __syncthreads();
#pragma unroll
    for (int k = 0; k < 16; k++) {
      float4 a = *(const float4*)&Xs[k][eg * 4];
      float4 b = *(const float4*)&Ws[k][og * 4];
      float ar[4] = {a.x, a.y, a.z, a.w};
      float br_[4] = {b.x, b.y, b.z, b.w};
#pragma unroll
      for (int i = 0; i < 4; i++)
#pragma unroll
        for (int j = 0; j < 4; j++) acc[i][j] += ar[i] * br_[j];
    }
  }
#pragma unroll
  for (int i = 0; i < 4; i++) {
    int row = m0 + eg * 4 + i;
    if (row < NN) {
#pragma unroll
      for (int j = 0; j < 4; j++) {
        int o = og * 4 + j;
        float v = acc[i][j] + agg1[(size_t)row * D2 + o] + bias1[o];
        h[(size_t)row * D2 + o] = fmaxf(v, 0.f);
      }
    }
  }
}

// ---------------------------------------------------------------------------
// out = h @ root2 + agg2 + bias2   tile 256 rows x 20 outs, K=64, 320 threads
// ---------------------------------------------------------------------------
__global__ __launch_bounds__(320) void out_kernel(
    const float* __restrict__ hbuf, const float* __restrict__ root2,
    const float* __restrict__ agg2, const float* __restrict__ bias2,
    float* __restrict__ out) {
  const int m0 = blockIdx.x * 256;
  __shared__ __align__(16) float Xs[16][260];
  __shared__ __align__(16) float Ws[16][20];
  const int tid = threadIdx.x;
  const int og = tid / 64;
  const int eg = tid % 64;

  float acc[4][4];
#pragma unroll
  for (int i = 0; i < 4; i++)
#pragma unroll
    for (int j = 0; j < 4; j++) acc[i][j] = 0.f;

  for (int kc = 0; kc < 4; kc++) {
    const int kb = kc * 16;
    __syncthreads();
    if (tid < 256) {
      const int q = tid & 3;
#pragma unroll
      for (int p = 0; p < 4; p++) {
        int e = p * 64 + (tid >> 2);
        int row = m0 + e;
        if (row >= NN) row = NN - 1;
        float4 v = *(const float4*)&hbuf[(size_t)row * D2 + kb + q * 4];
        Xs[q * 4 + 0][e] = v.x;
        Xs[q * 4 + 1][e] = v.y;
        Xs[q * 4 + 2][e] = v.z;
        Xs[q * 4 + 3][e] = v.w;
      }
    } else {
      int t = tid - 256;
#pragma unroll
      for (int p = 0; p < 5; p++) {
        int idx = p * 64 + t;
        int row = idx / 20, c = idx - row * 20;
        Ws[row][c] = root2[(size_t)(kb + row) * D3 + c];
      }
    }
    __syncthreads();
#pragma unroll
    for (int k = 0; k < 16; k++) {
      float4 a = *(const float4*)&Xs[k][eg * 4];
      float4 b = *(const float4*)&Ws[k][og * 4];
      float ar[4] = {a.x, a.y, a.z, a.w};
      float br_[4] = {b.x, b.y, b.z, b.w};
#pragma unroll
      for (int i = 0; i < 4; i++)
#pragma unroll
        for (int j = 0; j < 4; j++) acc[i][j] += ar[i] * br_[j];
    }
  }
#pragma unroll
  for (int i = 0; i < 4; i++) {
    int row = m0 + eg * 4 + i;
    if (row < NN) {
#pragma unroll
      for (int j = 0; j < 4; j++) {
        int o = og * 4 + j;
        out[(size_t)row * D3 + o] =
            acc[i][j] + agg2[(size_t)row * D3 + o] + bias2[o];
      }
    }
  }
}

// ---------------------------------------------------------------------------
extern "C" void kernel_launch(void* const* d_in, const int* in_sizes, int n_in,
                              void* d_out, int out_size, void* d_ws,
                              size_t ws_size, hipStream_t stream) {
  const float* x_drug = (const float*)d_in[0];
  const float* drug_w = (const float*)d_in[1];
  const int* ei       = (const int*)d_in[2];
  const float* basis1 = (const float*)d_in[3];
  const float* comp1  = (const float*)d_in[4];
  const float* root1  = (const float*)d_in[5];
  const float* bias1  = (const float*)d_in[6];
  const float* basis2 = (const float*)d_in[7];
  const float* comp2  = (const float*)d_in[8];
  const float* root2  = (const float*)d_in[9];
  const float* bias2  = (const float*)d_in[10];
  float* out = (float*)d_out;

  float* ws   = (float*)d_ws;
  float* x    = ws;                   // 1,280,000
  float* U1   = x + 1280000;          // 5,120,000 (U2 + agg2 alias inside later)
  float* h    = U1 + 5120000;         // 640,000
  float* agg1 = h + 640000;           // 640,000
  float* Bt1  = agg1 + 640000;        // 65,536
  float* Bt2  = Bt1 + 65536;          // 12,288
  int*  deg   = (int*)(Bt2 + 12288);  // 1,000,000
  int*  cnt   = deg + 1000000;        // 10,016
  int*  off   = cnt + 10016;          // 10,016
  int*  cur   = off + 10016;          // 10,016
  int*  rec   = cur + 10016;          // 500,000
  float* esc  = (float*)(rec + 500000); // 500,000
  float* U2   = U1;                   // 10000 x 192 = 1,920,000 (aliases U1)
  float* agg2 = U1 + 1920000;         // 200,000 (aliases U1 tail)

  hipMemsetAsync(x,   0, (size_t)1280000 * 4, stream);
  hipMemsetAsync(deg, 0, (size_t)1000000 * 4, stream);
  hipMemsetAsync(cnt, 0, (size_t)10016 * 4, stream);

  // CSR build (shared by both layers)
  count_kernel<<<(NE + 255) / 256, 256, 0, stream>>>(ei, cnt, deg);
  scan_kernel<<<1, 1024, 0, stream>>>(cnt, off, cur);
  scatter_kernel<<<(NE + 255) / 256, 256, 0, stream>>>(ei, deg, cur, rec, esc);

  // x = x_drug @ drug_w
  gemm0_kernel<<<dim3(157, 4), 256, 0, stream>>>(x_drug, drug_w, x);

  // layer 1
  t_basis1_kernel<<<(8 * 128 * 64 + 255) / 256, 256, 0, stream>>>(basis1, Bt1);
  gemm_tile_kernel<<<dim3(157, 8), 256, 0, stream>>>(x, Bt1, U1, 128, 512);
  agg1_kernel<<<(NN + 3) / 4, 256, 0, stream>>>(U1, off, rec, esc, comp1, agg1);
  hlayer_kernel<<<(NN + 63) / 64, 256, 0, stream>>>(x, root1, agg1, bias1, h);

  // layer 2 (U2/agg2 reuse U1's buffer; U1 fully consumed above)
  t_basis2_kernel<<<(64 * 192 + 255) / 256, 256, 0, stream>>>(basis2, Bt2);
  gemm_tile_kernel<<<dim3(157, 3), 256, 0, stream>>>(h, Bt2, U2, 64, 192);
  agg2_kernel<<<(NN + 3) / 4, 256, 0, stream>>>(U2, off, rec, esc, comp2, agg2);
  out_kernel<<<(NN + 255) / 256, 320, 0, stream>>>(h, root2, agg2, bias2, out);
}

// Round 3
// 376.526 us; speedup vs baseline: 13.1348x; 1.5080x over previous
//
#include <hip/hip_runtime.h>

#define NN 10000    // nodes
#define RR 100      // relations
#define EE 5000     // edges per relation
#define D0 2048
#define D1 128
#define D2 64
#define D3 20
#define NE (RR*EE)  // 500000 edges total

using short8  = __attribute__((ext_vector_type(8))) short;
using float4e = __attribute__((ext_vector_type(4))) float;

__device__ __forceinline__ unsigned short f2bf(float f) {
  unsigned int u = __float_as_uint(f);
  unsigned int r = u + 0x7fffu + ((u >> 16) & 1u);   // RNE
  return (unsigned short)(r >> 16);
}
__device__ __forceinline__ float bf2f(unsigned short u) {
  return __uint_as_float(((unsigned int)u) << 16);
}

// ---------------------------------------------------------------------------
// CSR build
// ---------------------------------------------------------------------------
__global__ void deg_kernel(const int* __restrict__ ei, int* __restrict__ deg) {
  int gid = blockIdx.x * 256 + threadIdx.x;
  if (gid >= NE) return;
  int r = gid / EE, e = gid - r * EE;
  int d = ei[r * 2 * EE + EE + e];
  atomicAdd(&deg[r * NN + d], 1);
}

__global__ void cnt_kernel(const int* __restrict__ deg, int* __restrict__ cnt) {
  int n = blockIdx.x * 256 + threadIdx.x;
  if (n >= NN) return;
  int s = 0;
  for (int r = 0; r < RR; r++) s += deg[r * NN + n];
  cnt[n] = s;
}

__global__ __launch_bounds__(1024) void scan_kernel(const int* __restrict__ cnt,
                                                    int* __restrict__ off,
                                                    int* __restrict__ cur) {
  __shared__ int wsum[16];
  __shared__ int carry_s;
  const int tid = threadIdx.x;
  const int wv = tid >> 6, lane = tid & 63;
  if (tid == 0) carry_s = 0;
  __syncthreads();
  for (int base = 0; base < NN; base += 1024) {
    int i = base + tid;
    int v = (i < NN) ? cnt[i] : 0;
    int s = v;
#pragma unroll
    for (int d = 1; d < 64; d <<= 1) {
      int t = __shfl_up(s, d, 64);
      if (lane >= d) s += t;
    }
    if (lane == 63) wsum[wv] = s;
    __syncthreads();
    if (wv == 0) {
      int w = (lane < 16) ? wsum[lane] : 0;
#pragma unroll
      for (int d = 1; d < 16; d <<= 1) {
        int t = __shfl_up(w, d, 64);
        if (lane >= d) w += t;
      }
      if (lane < 16) wsum[lane] = w;
    }
    __syncthreads();
    int excl = carry_s + (wv > 0 ? wsum[wv - 1] : 0) + s - v;
    if (i < NN) { off[i] = excl; cur[i] = excl; }
    __syncthreads();
    if (tid == 1023) carry_s += wsum[15];
    __syncthreads();
  }
  if (tid == 0) off[NN] = carry_s;
}

// rec = (r<<14)|src, esc = 1/max(deg,1)
__global__ void scatter_kernel(const int* __restrict__ ei,
                               const int* __restrict__ deg,
                               int* __restrict__ cur, int* __restrict__ rec,
                               float* __restrict__ esc) {
  int gid = blockIdx.x * 256 + threadIdx.x;
  if (gid >= NE) return;
  int r = gid / EE, e = gid - r * EE;
  int s = ei[r * 2 * EE + e];
  int d = ei[r * 2 * EE + EE + e];
  int p = atomicAdd(&cur[d], 1);
  rec[p] = (r << 14) | s;
  esc[p] = 1.0f / fmaxf((float)deg[r * NN + d], 1.0f);
}

// ---------------------------------------------------------------------------
// weight prep (bf16, transposed [n][k] for MFMA B-frag loads)
// ---------------------------------------------------------------------------
__global__ void wtrans_kernel(const float* __restrict__ W,
                              unsigned short* __restrict__ Bt) {
  int idx = blockIdx.x * 256 + threadIdx.x;
  if (idx >= 128 * 2048) return;
  int n = idx >> 11, k = idx & 2047;
  Bt[idx] = f2bf(W[(size_t)k * 128 + n]);
}

// Wc1T[o][j] : j<128 -> root1[j][o], else basis1 flat[(j-128)][o]; [64][1152]
__global__ void wc1t_kernel(const float* __restrict__ root1,
                            const float* __restrict__ basis1,
                            unsigned short* __restrict__ Wt) {
  int idx = blockIdx.x * 256 + threadIdx.x;
  if (idx >= 64 * 1152) return;
  int o = idx / 1152, j = idx - o * 1152;
  float v = (j < 128) ? root1[j * 64 + o] : basis1[(j - 128) * 64 + o];
  Wt[idx] = f2bf(v);
}

// Wc2T[c][j] : c<20: (j<64 -> root2[j][c], else basis2 flat[(j-64)][c]); [32][576]
__global__ void wc2t_kernel(const float* __restrict__ root2,
                            const float* __restrict__ basis2,
                            unsigned short* __restrict__ Wt) {
  int idx = blockIdx.x * 256 + threadIdx.x;
  if (idx >= 32 * 576) return;
  int c = idx / 576, j = idx - c * 576;
  float v = 0.f;
  if (c < 20) v = (j < 64) ? root2[j * 20 + c] : basis2[(j - 64) * 20 + c];
  Wt[idx] = f2bf(v);
}

// ---------------------------------------------------------------------------
// gemm0: xp[ks] = x_drug[:, ks*1024:(ks+1)*1024] @ drug_w[ks*1024:,:]
// bf16 MFMA 16x16x32; tile M=64,N=128; in-kernel fp32->bf16 convert
// ---------------------------------------------------------------------------
__global__ __launch_bounds__(256) void gemm0_mfma(
    const float* __restrict__ A, const unsigned short* __restrict__ Btw,
    float* __restrict__ xp) {
  __shared__ unsigned short Asb[64][40];
  __shared__ unsigned short Bsb[128][40];
  const int tid = threadIdx.x;
  const int m0 = blockIdx.x * 64;
  const int ks = blockIdx.y;
  const int wv = tid >> 6, lane = tid & 63;
  const int lrow = lane & 15, quad = lane >> 4;

  float4e acc[8];
#pragma unroll
  for (int i = 0; i < 8; i++) { acc[i][0]=0.f; acc[i][1]=0.f; acc[i][2]=0.f; acc[i][3]=0.f; }

  for (int c = 0; c < 32; c++) {
    const int kb = ks * 1024 + c * 32;
    __syncthreads();
#pragma unroll
    for (int p = 0; p < 2; p++) {  // A: 64 rows x 32 fp32 -> bf16
      int idx = p * 256 + tid;
      int row = idx >> 3, q = idx & 7;
      int gr = m0 + row; if (gr >= NN) gr = NN - 1;
      float4 v = *(const float4*)&A[(size_t)gr * D0 + kb + q * 4];
      ushort4 pk; pk.x = f2bf(v.x); pk.y = f2bf(v.y); pk.z = f2bf(v.z); pk.w = f2bf(v.w);
      *(ushort4*)&Asb[row][q * 4] = pk;
    }
#pragma unroll
    for (int p = 0; p < 2; p++) {  // B^T: 128 rows x 32 bf16
      int idx = p * 256 + tid;
      int row = idx >> 2, q = idx & 3;
      *(uint4*)&Bsb[row][q * 8] = *(const uint4*)&Btw[(size_t)row * D0 + kb + q * 8];
    }
    __syncthreads();
    short8 af = *(const short8*)&Asb[wv * 16 + lrow][quad * 8];
#pragma unroll
    for (int nt = 0; nt < 8; nt++) {
      short8 bfr = *(const short8*)&Bsb[nt * 16 + lrow][quad * 8];
      acc[nt] = __builtin_amdgcn_mfma_f32_16x16x32_bf16(af, bfr, acc[nt], 0, 0, 0);
    }
  }
#pragma unroll
  for (int nt = 0; nt < 8; nt++) {
    int col = nt * 16 + lrow;
#pragma unroll
    for (int r = 0; r < 4; r++) {
      int row = m0 + wv * 16 + quad * 4 + r;
      if (row < NN)
        xp[(size_t)ks * (NN * D1) + (size_t)row * D1 + col] = acc[nt][r];
    }
  }
}

// xb = bf16(xp[0] + xp[1])
__global__ void reduce_kernel(const float* __restrict__ xp,
                              unsigned short* __restrict__ xb) {
  int idx = (blockIdx.x * 256 + threadIdx.x) * 4;
  if (idx >= NN * D1) return;
  float4 a = *(const float4*)&xp[idx];
  float4 b = *(const float4*)&xp[NN * D1 + idx];
  ushort4 o;
  o.x = f2bf(a.x + b.x); o.y = f2bf(a.y + b.y);
  o.z = f2bf(a.z + b.z); o.w = f2bf(a.w + b.w);
  *(ushort4*)&xb[idx] = o;
}

// ---------------------------------------------------------------------------
// agg1e: A1b[n, b*128+i] = bf16( sum_{e->n} esc_e*comp1[r_e,b]*x[src_e,i] )
// one wave per node; lane holds 2 of 128 x-channels; 8 b-accumulators
// ---------------------------------------------------------------------------
__global__ __launch_bounds__(256) void agg1e_kernel(
    const unsigned short* __restrict__ xb, const int* __restrict__ off,
    const int* __restrict__ rec, const float* __restrict__ esc,
    const float* __restrict__ comp, unsigned short* __restrict__ A1b) {
  __shared__ float s_comp[RR * 8];
  const int tid = threadIdx.x;
  for (int i = tid; i < RR * 8; i += 256) s_comp[i] = comp[i];
  __syncthreads();
  const int wv = tid >> 6, lane = tid & 63;
  const int n = blockIdx.x * 4 + wv;
  if (n >= NN) return;
  float acc[8][2];
#pragma unroll
  for (int b = 0; b < 8; b++) { acc[b][0] = 0.f; acc[b][1] = 0.f; }
  const int beg = off[n], end = off[n + 1];
  int idx = beg;
  for (; idx + 1 < end; idx += 2) {
    int rc0 = rec[idx], rc1 = rec[idx + 1];
    float sc0 = esc[idx], sc1 = esc[idx + 1];
    unsigned int xv0 = *(const unsigned int*)&xb[(size_t)(rc0 & 16383) * D1 + lane * 2];
    unsigned int xv1 = *(const unsigned int*)&xb[(size_t)(rc1 & 16383) * D1 + lane * 2];
    const float* c0 = &s_comp[(rc0 >> 14) * 8];
    const float* c1 = &s_comp[(rc1 >> 14) * 8];
    float x00 = __uint_as_float((xv0 & 0xffffu) << 16);
    float x01 = __uint_as_float(xv0 & 0xffff0000u);
    float x10 = __uint_as_float((xv1 & 0xffffu) << 16);
    float x11 = __uint_as_float(xv1 & 0xffff0000u);
#pragma unroll
    for (int b = 0; b < 8; b++) {
      float w0 = sc0 * c0[b], w1 = sc1 * c1[b];
      acc[b][0] += w0 * x00 + w1 * x10;
      acc[b][1] += w0 * x01 + w1 * x11;
    }
  }
  if (idx < end) {
    int rc = rec[idx];
    float sc = esc[idx];
    unsigned int xv = *(const unsigned int*)&xb[(size_t)(rc & 16383) * D1 + lane * 2];
    const float* c0 = &s_comp[(rc >> 14) * 8];
    float x0 = __uint_as_float((xv & 0xffffu) << 16);
    float x1 = __uint_as_float(xv & 0xffff0000u);
#pragma unroll
    for (int b = 0; b < 8; b++) {
      float w = sc * c0[b];
      acc[b][0] += w * x0;
      acc[b][1] += w * x1;
    }
  }
#pragma unroll
  for (int b = 0; b < 8; b++) {
    ushort2 o; o.x = f2bf(acc[b][0]); o.y = f2bf(acc[b][1]);
    *(ushort2*)&A1b[(size_t)n * 1024 + b * 128 + lane * 2] = o;
  }
}

// ---------------------------------------------------------------------------
// agg2e: A2b[n, b*64+i] = bf16( sum_{e->n} esc_e*comp2[r_e,b]*h[src_e,i] )
// ---------------------------------------------------------------------------
__global__ __launch_bounds__(256) void agg2e_kernel(
    const unsigned short* __restrict__ hb, const int* __restrict__ off,
    const int* __restrict__ rec, const float* __restrict__ esc,
    const float* __restrict__ comp, unsigned short* __restrict__ A2b) {
  __shared__ float s_comp[RR * 8];
  const int tid = threadIdx.x;
  for (int i = tid; i < RR * 8; i += 256) s_comp[i] = comp[i];
  __syncthreads();
  const int wv = tid >> 6, lane = tid & 63;
  const int n = blockIdx.x * 4 + wv;
  if (n >= NN) return;
  float acc[8];
#pragma unroll
  for (int b = 0; b < 8; b++) acc[b] = 0.f;
  const int beg = off[n], end = off[n + 1];
  int idx = beg;
  for (; idx + 1 < end; idx += 2) {
    int rc0 = rec[idx], rc1 = rec[idx + 1];
    float sc0 = esc[idx], sc1 = esc[idx + 1];
    float h0 = bf2f(hb[(size_t)(rc0 & 16383) * D2 + lane]);
    float h1 = bf2f(hb[(size_t)(rc1 & 16383) * D2 + lane]);
    const float* c0 = &s_comp[(rc0 >> 14) * 8];
    const float* c1 = &s_comp[(rc1 >> 14) * 8];
#pragma unroll
    for (int b = 0; b < 8; b++)
      acc[b] += sc0 * c0[b] * h0 + sc1 * c1[b] * h1;
  }
  if (idx < end) {
    int rc = rec[idx];
    float sc = esc[idx];
    float h0 = bf2f(hb[(size_t)(rc & 16383) * D2 + lane]);
    const float* c0 = &s_comp[(rc >> 14) * 8];
#pragma unroll
    for (int b = 0; b < 8; b++) acc[b] += sc * c0[b] * h0;
  }
#pragma unroll
  for (int b = 0; b < 8; b++)
    A2b[(size_t)n * 512 + b * 64 + lane] = f2bf(acc[b]);
}

// ---------------------------------------------------------------------------
// hlayer: hb = bf16(relu([xb|A1b](K=1152) @ Wc1T + bias1)); MFMA, tile 64x64
// ---------------------------------------------------------------------------
__global__ __launch_bounds__(256) void hlayer_mfma(
    const unsigned short* __restrict__ xb, const unsigned short* __restrict__ A1b,
    const unsigned short* __restrict__ Wt, const float* __restrict__ bias1,
    unsigned short* __restrict__ hb) {
  __shared__ unsigned short Asb[64][40];
  __shared__ unsigned short Bsb[64][40];
  const int tid = threadIdx.x;
  const int m0 = blockIdx.x * 64;
  const int wv = tid >> 6, lane = tid & 63;
  const int lrow = lane & 15, quad = lane >> 4;

  float4e acc[4];
#pragma unroll
  for (int i = 0; i < 4; i++) { acc[i][0]=0.f; acc[i][1]=0.f; acc[i][2]=0.f; acc[i][3]=0.f; }

  const int row_s = tid >> 2, q_s = tid & 3;
  int gr = m0 + row_s; if (gr >= NN) gr = NN - 1;

  for (int c = 0; c < 36; c++) {
    const int kb = c * 32;
    __syncthreads();
    {
      const unsigned short* sp = (kb < 128)
          ? &xb[(size_t)gr * D1 + kb + q_s * 8]
          : &A1b[(size_t)gr * 1024 + (kb - 128) + q_s * 8];
      *(uint4*)&Asb[row_s][q_s * 8] = *(const uint4*)sp;
      *(uint4*)&Bsb[row_s][q_s * 8] = *(const uint4*)&Wt[(size_t)row_s * 1152 + kb + q_s * 8];
    }
    __syncthreads();
    short8 af = *(const short8*)&Asb[wv * 16 + lrow][quad * 8];
#pragma unroll
    for (int nt = 0; nt < 4; nt++) {
      short8 bfr = *(const short8*)&Bsb[nt * 16 + lrow][quad * 8];
      acc[nt] = __builtin_amdgcn_mfma_f32_16x16x32_bf16(af, bfr, acc[nt], 0, 0, 0);
    }
  }
#pragma unroll
  for (int nt = 0; nt < 4; nt++) {
    int col = nt * 16 + lrow;
    float bv = bias1[col];
#pragma unroll
    for (int r = 0; r < 4; r++) {
      int row = m0 + wv * 16 + quad * 4 + r;
      if (row < NN)
        hb[(size_t)row * D2 + col] = f2bf(fmaxf(acc[nt][r] + bv, 0.f));
    }
  }
}

// ---------------------------------------------------------------------------
// out: out = [hb|A2b](K=576) @ Wc2T + bias2; MFMA, tile 64x32, cols 20..31 dropped
// ---------------------------------------------------------------------------
__global__ __launch_bounds__(256) void out_mfma(
    const unsigned short* __restrict__ hb, const unsigned short* __restrict__ A2b,
    const unsigned short* __restrict__ Wt, const float* __restrict__ bias2,
    float* __restrict__ out) {
  __shared__ unsigned short Asb[64][40];
  __shared__ unsigned short Bsb[32][40];
  const int tid = threadIdx.x;
  const int m0 = blockIdx.x * 64;
  const int wv = tid >> 6, lane = tid & 63;
  const int lrow = lane & 15, quad = lane >> 4;

  float4e acc[2];
#pragma unroll
  for (int i = 0; i < 2; i++) { acc[i][0]=0.f; acc[i][1]=0.f; acc[i][2]=0.f; acc[i][3]=0.f; }

  const int row_s = tid >> 2, q_s = tid & 3;
  int gr = m0 + row_s; if (gr >= NN) gr = NN - 1;

  for (int c = 0; c < 18; c++) {
    const int kb = c * 32;
    __syncthreads();
    {
      const unsigned short* sp = (kb < 64)
          ? &hb[(size_t)gr * D2 + kb + q_s * 8]
          : &A2b[(size_t)gr * 512 + (kb - 64) + q_s * 8];
      *(uint4*)&Asb[row_s][q_s * 8] = *(const uint4*)sp;
    }
    if (tid < 128) {
      int rw = tid >> 2, qw = tid & 3;
      *(uint4*)&Bsb[rw][qw * 8] = *(const uint4*)&Wt[(size_t)rw * 576 + kb + qw * 8];
    }
    __syncthreads();
    short8 af = *(const short8*)&Asb[wv * 16 + lrow][quad * 8];
#pragma unroll
    for (int nt = 0; nt < 2; nt++) {
      short8 bfr = *(const short8*)&Bsb[nt * 16 + lrow][quad * 8];
      acc[nt] = __builtin_amdgcn_mfma_f32_16x16x32_bf16(af, bfr, acc[nt], 0, 0, 0);
    }
  }
#pragma unroll
  for (int nt = 0; nt < 2; nt++) {
    int col = nt * 16 + lrow;
    if (col < D3) {
      float bv = bias2[col];
#pragma unroll
      for (int r = 0; r < 4; r++) {
        int row = m0 + wv * 16 + quad * 4 + r;
        if (row < NN)
          out[(size_t)row * D3 + col] = acc[nt][r] + bv;
      }
    }
  }
}

// ---------------------------------------------------------------------------
extern "C" void kernel_launch(void* const* d_in, const int* in_sizes, int n_in,
                              void* d_out, int out_size, void* d_ws,
                              size_t ws_size, hipStream_t stream) {
  const float* x_drug = (const float*)d_in[0];
  const float* drug_w = (const float*)d_in[1];
  const int*   ei     = (const int*)d_in[2];
  const float* basis1 = (const float*)d_in[3];
  const float* comp1  = (const float*)d_in[4];
  const float* root1  = (const float*)d_in[5];
  const float* bias1  = (const float*)d_in[6];
  const float* basis2 = (const float*)d_in[7];
  const float* comp2  = (const float*)d_in[8];
  const float* root2  = (const float*)d_in[9];
  const float* bias2  = (const float*)d_in[10];
  float* out = (float*)d_out;

  // workspace layout (float-equivalent units; peak ~33 MB)
  float* ws = (float*)d_ws;
  int*   deg  = (int*)ws;                          // 1,000,000
  int*   cnt  = deg + 1000000;                     // 10,016
  int*   off  = cnt + 10016;                       // 10,016
  int*   cur  = off + 10016;                       // 10,016
  int*   rec  = cur + 10016;                       // 500,000
  float* esc  = (float*)(rec + 500000);            // 500,000
  unsigned short* xb   = (unsigned short*)(esc + 500000);      // 1,280,000 us (640,000 f)
  unsigned short* hb   = (unsigned short*)((float*)xb + 640000);   // 640,000 us (320,000 f)
  unsigned short* Btw  = (unsigned short*)((float*)hb + 320000);   // 262,144 us (131,072 f)
  unsigned short* Wc1T = (unsigned short*)((float*)Btw + 131072);  // 73,728 us (36,864 f)
  unsigned short* Wc2T = (unsigned short*)((float*)Wc1T + 36864);  // 18,432 us (9,216 f)
  float* R1 = (float*)Wc2T + 9216;                 // 5,120,000 floats shared region
  float* xp = R1;                                  // 2 x 1,280,000 fp32 partials
  unsigned short* A1b = (unsigned short*)R1;       // 10,240,000 us (after xp dead)
  unsigned short* A2b = (unsigned short*)R1;       // 5,120,000 us (after A1b dead)

  hipMemsetAsync(deg, 0, (size_t)1000000 * 4, stream);

  // CSR build
  deg_kernel<<<(NE + 255) / 256, 256, 0, stream>>>(ei, deg);
  cnt_kernel<<<(NN + 255) / 256, 256, 0, stream>>>(deg, cnt);
  scan_kernel<<<1, 1024, 0, stream>>>(cnt, off, cur);
  scatter_kernel<<<(NE + 255) / 256, 256, 0, stream>>>(ei, deg, cur, rec, esc);

  // weights
  wtrans_kernel<<<(128 * 2048 + 255) / 256, 256, 0, stream>>>(drug_w, Btw);
  wc1t_kernel<<<(64 * 1152 + 255) / 256, 256, 0, stream>>>(root1, basis1, Wc1T);
  wc2t_kernel<<<(32 * 576 + 255) / 256, 256, 0, stream>>>(root2, basis2, Wc2T);

  // x = x_drug @ drug_w (bf16 MFMA, K-split 2 + reduce)
  gemm0_mfma<<<dim3(157, 2), 256, 0, stream>>>(x_drug, Btw, xp);
  reduce_kernel<<<(NN * D1 / 4 + 255) / 256, 256, 0, stream>>>(xp, xb);

  // layer 1
  agg1e_kernel<<<(NN + 3) / 4, 256, 0, stream>>>(xb, off, rec, esc, comp1, A1b);
  hlayer_mfma<<<157, 256, 0, stream>>>(xb, A1b, Wc1T, bias1, hb);

  // layer 2
  agg2e_kernel<<<(NN + 3) / 4, 256, 0, stream>>>(hb, off, rec, esc, comp2, A2b);
  out_mfma<<<157, 256, 0, stream>>>(hb, A2b, Wc2T, bias2, out);
}

// Round 4
// 341.963 us; speedup vs baseline: 14.4624x; 1.1011x over previous
//
#include <hip/hip_runtime.h>

#define NN 10000    // nodes
#define RR 100      // relations
#define EE 5000     // edges per relation
#define D0 2048
#define D1 128
#define D2 64
#define D3 20
#define NE (RR*EE)  // 500000 edges total

using short8  = __attribute__((ext_vector_type(8))) short;
using float4e = __attribute__((ext_vector_type(4))) float;

__device__ __forceinline__ unsigned short f2bf(float f) {
  unsigned int u = __float_as_uint(f);
  unsigned int r = u + 0x7fffu + ((u >> 16) & 1u);   // RNE
  return (unsigned short)(r >> 16);
}
__device__ __forceinline__ float bf2f(unsigned short u) {
  return __uint_as_float(((unsigned int)u) << 16);
}
__device__ __forceinline__ unsigned int pk2(float lo, float hi) {
  return ((unsigned int)f2bf(hi) << 16) | (unsigned int)f2bf(lo);
}

// ---------------------------------------------------------------------------
// CSR build
// ---------------------------------------------------------------------------
__global__ void deg_kernel(const int* __restrict__ ei, int* __restrict__ deg) {
  int gid = blockIdx.x * 256 + threadIdx.x;
  if (gid >= NE) return;
  int r = gid / EE, e = gid - r * EE;
  int d = ei[r * 2 * EE + EE + e];
  atomicAdd(&deg[r * NN + d], 1);
}

__global__ void cnt_kernel(const int* __restrict__ deg, int* __restrict__ cnt) {
  int n = blockIdx.x * 256 + threadIdx.x;
  if (n >= NN) return;
  int s = 0;
  for (int r = 0; r < RR; r++) s += deg[r * NN + n];
  cnt[n] = s;
}

__global__ __launch_bounds__(1024) void scan_kernel(const int* __restrict__ cnt,
                                                    int* __restrict__ off,
                                                    int* __restrict__ cur) {
  __shared__ int wsum[16];
  __shared__ int carry_s;
  const int tid = threadIdx.x;
  const int wv = tid >> 6, lane = tid & 63;
  if (tid == 0) carry_s = 0;
  __syncthreads();
  for (int base = 0; base < NN; base += 1024) {
    int i = base + tid;
    int v = (i < NN) ? cnt[i] : 0;
    int s = v;
#pragma unroll
    for (int d = 1; d < 64; d <<= 1) {
      int t = __shfl_up(s, d, 64);
      if (lane >= d) s += t;
    }
    if (lane == 63) wsum[wv] = s;
    __syncthreads();
    if (wv == 0) {
      int w = (lane < 16) ? wsum[lane] : 0;
#pragma unroll
      for (int d = 1; d < 16; d <<= 1) {
        int t = __shfl_up(w, d, 64);
        if (lane >= d) w += t;
      }
      if (lane < 16) wsum[lane] = w;
    }
    __syncthreads();
    int excl = carry_s + (wv > 0 ? wsum[wv - 1] : 0) + s - v;
    if (i < NN) { off[i] = excl; cur[i] = excl; }
    __syncthreads();
    if (tid == 1023) carry_s += wsum[15];
    __syncthreads();
  }
  if (tid == 0) off[NN] = carry_s;
}

// rec = (r<<14)|src, esc = 1/max(deg,1)
__global__ void scatter_kernel(const int* __restrict__ ei,
                               const int* __restrict__ deg,
                               int* __restrict__ cur, int* __restrict__ rec,
                               float* __restrict__ esc) {
  int gid = blockIdx.x * 256 + threadIdx.x;
  if (gid >= NE) return;
  int r = gid / EE, e = gid - r * EE;
  int s = ei[r * 2 * EE + e];
  int d = ei[r * 2 * EE + EE + e];
  int p = atomicAdd(&cur[d], 1);
  rec[p] = (r << 14) | s;
  esc[p] = 1.0f / fmaxf((float)deg[r * NN + d], 1.0f);
}

// ---------------------------------------------------------------------------
// weight prep (bf16, transposed [n][k] for MFMA B-frag loads)
// ---------------------------------------------------------------------------
__global__ void wtrans_kernel(const float* __restrict__ W,
                              unsigned short* __restrict__ Bt) {
  int idx = blockIdx.x * 256 + threadIdx.x;
  if (idx >= 128 * 2048) return;
  int n = idx >> 11, k = idx & 2047;
  Bt[idx] = f2bf(W[(size_t)k * 128 + n]);
}

__global__ void wc1t_kernel(const float* __restrict__ root1,
                            const float* __restrict__ basis1,
                            unsigned short* __restrict__ Wt) {
  int idx = blockIdx.x * 256 + threadIdx.x;
  if (idx >= 64 * 1152) return;
  int o = idx / 1152, j = idx - o * 1152;
  float v = (j < 128) ? root1[j * 64 + o] : basis1[(j - 128) * 64 + o];
  Wt[idx] = f2bf(v);
}

__global__ void wc2t_kernel(const float* __restrict__ root2,
                            const float* __restrict__ basis2,
                            unsigned short* __restrict__ Wt) {
  int idx = blockIdx.x * 256 + threadIdx.x;
  if (idx >= 32 * 576) return;
  int c = idx / 576, j = idx - c * 576;
  float v = 0.f;
  if (c < 20) v = (j < 64) ? root2[j * 20 + c] : basis2[(j - 64) * 20 + c];
  Wt[idx] = f2bf(v);
}

// ---------------------------------------------------------------------------
// gemm0: xp[ks] = x_drug[:, ks*512:+512] @ drug_w[ks*512:,:]  (K-split 4)
// bf16 MFMA 16x16x32; tile M=64,N=128; register-prefetch pipeline
// ---------------------------------------------------------------------------
__global__ __launch_bounds__(256) void gemm0_mfma(
    const float* __restrict__ A, const unsigned short* __restrict__ Btw,
    float* __restrict__ xp) {
  __shared__ unsigned short Asb[64][40];
  __shared__ unsigned short Bsb[128][40];
  const int tid = threadIdx.x;
  const int m0 = blockIdx.x * 64;
  const int ks = blockIdx.y;
  const int wv = tid >> 6, lane = tid & 63;
  const int lrow = lane & 15, quad = lane >> 4;

  const int arow = tid >> 2, aq = tid & 3;
  int gr = m0 + arow; if (gr >= NN) gr = NN - 1;
  const float* Aptr = &A[(size_t)gr * D0 + ks * 512 + aq * 8];
  const unsigned short* Bp0 = &Btw[(size_t)arow * D0 + ks * 512 + aq * 8];
  const unsigned short* Bp1 = &Btw[(size_t)(arow + 64) * D0 + ks * 512 + aq * 8];

  float4 ra0[2], ra1[2];
  uint4 rb0[2], rb1[2];

#define G0_LOAD(ra, rb, c)                               \
  { ra[0] = *(const float4*)(Aptr + (c) * 32);           \
    ra[1] = *(const float4*)(Aptr + (c) * 32 + 4);       \
    rb[0] = *(const uint4*)(Bp0 + (c) * 32);             \
    rb[1] = *(const uint4*)(Bp1 + (c) * 32); }

#define G0_STORE(ra, rb)                                                   \
  { uint4 pk;                                                              \
    pk.x = pk2(ra[0].x, ra[0].y); pk.y = pk2(ra[0].z, ra[0].w);            \
    pk.z = pk2(ra[1].x, ra[1].y); pk.w = pk2(ra[1].z, ra[1].w);            \
    *(uint4*)&Asb[arow][aq * 8] = pk;                                      \
    *(uint4*)&Bsb[arow][aq * 8] = rb[0];                                   \
    *(uint4*)&Bsb[arow + 64][aq * 8] = rb[1]; }

#define G0_COMPUTE()                                                        \
  { short8 af = *(const short8*)&Asb[wv * 16 + lrow][quad * 8];             \
    _Pragma("unroll")                                                       \
    for (int nt = 0; nt < 8; nt++) {                                        \
      short8 bfr = *(const short8*)&Bsb[nt * 16 + lrow][quad * 8];          \
      acc[nt] = __builtin_amdgcn_mfma_f32_16x16x32_bf16(af, bfr, acc[nt], 0, 0, 0); \
    } }

  float4e acc[8];
#pragma unroll
  for (int i = 0; i < 8; i++) { acc[i][0]=0.f; acc[i][1]=0.f; acc[i][2]=0.f; acc[i][3]=0.f; }

  G0_LOAD(ra0, rb0, 0);
  for (int c = 0; c < 16; c += 2) {
    G0_STORE(ra0, rb0);
    __syncthreads();
    if (c + 1 < 16) G0_LOAD(ra1, rb1, c + 1);
    G0_COMPUTE();
    __syncthreads();
    G0_STORE(ra1, rb1);
    __syncthreads();
    if (c + 2 < 16) G0_LOAD(ra0, rb0, c + 2);
    G0_COMPUTE();
    __syncthreads();
  }

#pragma unroll
  for (int nt = 0; nt < 8; nt++) {
    int col = nt * 16 + lrow;
#pragma unroll
    for (int r = 0; r < 4; r++) {
      int row = m0 + wv * 16 + quad * 4 + r;
      if (row < NN)
        xp[(size_t)ks * (NN * D1) + (size_t)row * D1 + col] = acc[nt][r];
    }
  }
}

// xb = bf16(xp0+xp1+xp2+xp3)
__global__ void reduce_kernel(const float* __restrict__ xp,
                              unsigned short* __restrict__ xb) {
  int idx = (blockIdx.x * 256 + threadIdx.x) * 4;
  if (idx >= NN * D1) return;
  float4 a = *(const float4*)&xp[idx];
  float4 b = *(const float4*)&xp[NN * D1 + idx];
  float4 c = *(const float4*)&xp[2 * NN * D1 + idx];
  float4 d = *(const float4*)&xp[3 * NN * D1 + idx];
  ushort4 o;
  o.x = f2bf(a.x + b.x + c.x + d.x); o.y = f2bf(a.y + b.y + c.y + d.y);
  o.z = f2bf(a.z + b.z + c.z + d.z); o.w = f2bf(a.w + b.w + c.w + d.w);
  *(ushort4*)&xb[idx] = o;
}

// ---------------------------------------------------------------------------
// agg1e: A1b[n, b*128+i] = bf16( sum_{e->n} esc_e*comp1[r_e,b]*x[src_e,i] )
// one wave per node; lane holds 2 of 128 channels; 4-edge unroll
// ---------------------------------------------------------------------------
__global__ __launch_bounds__(256) void agg1e_kernel(
    const unsigned short* __restrict__ xb, const int* __restrict__ off,
    const int* __restrict__ rec, const float* __restrict__ esc,
    const float* __restrict__ comp, unsigned short* __restrict__ A1b) {
  __shared__ float s_comp[RR * 8];
  const int tid = threadIdx.x;
  for (int i = tid; i < RR * 8; i += 256) s_comp[i] = comp[i];
  __syncthreads();
  const int wv = tid >> 6, lane = tid & 63;
  const int n = blockIdx.x * 4 + wv;
  if (n >= NN) return;
  float acc[8][2];
#pragma unroll
  for (int b = 0; b < 8; b++) { acc[b][0] = 0.f; acc[b][1] = 0.f; }
  const int beg = off[n], end = off[n + 1];
  int idx = beg;
  for (; idx + 3 < end; idx += 4) {
    int rc[4]; float sc[4]; unsigned int xv[4];
#pragma unroll
    for (int u = 0; u < 4; u++) {
      rc[u] = rec[idx + u];
      sc[u] = esc[idx + u];
    }
#pragma unroll
    for (int u = 0; u < 4; u++)
      xv[u] = *(const unsigned int*)&xb[(size_t)(rc[u] & 16383) * D1 + lane * 2];
#pragma unroll
    for (int u = 0; u < 4; u++) {
      const float* cb = &s_comp[(rc[u] >> 14) * 8];
      float x0 = __uint_as_float((xv[u] & 0xffffu) << 16);
      float x1 = __uint_as_float(xv[u] & 0xffff0000u);
#pragma unroll
      for (int b = 0; b < 8; b++) {
        float w = sc[u] * cb[b];
        acc[b][0] += w * x0;
        acc[b][1] += w * x1;
      }
    }
  }
  for (; idx < end; idx++) {
    int rc = rec[idx];
    float sc = esc[idx];
    unsigned int xv = *(const unsigned int*)&xb[(size_t)(rc & 16383) * D1 + lane * 2];
    const float* cb = &s_comp[(rc >> 14) * 8];
    float x0 = __uint_as_float((xv & 0xffffu) << 16);
    float x1 = __uint_as_float(xv & 0xffff0000u);
#pragma unroll
    for (int b = 0; b < 8; b++) {
      float w = sc * cb[b];
      acc[b][0] += w * x0;
      acc[b][1] += w * x1;
    }
  }
#pragma unroll
  for (int b = 0; b < 8; b++) {
    ushort2 o; o.x = f2bf(acc[b][0]); o.y = f2bf(acc[b][1]);
    *(ushort2*)&A1b[(size_t)n * 1024 + b * 128 + lane * 2] = o;
  }
}

// ---------------------------------------------------------------------------
// agg2e: A2b[n, b*64+i] = bf16( sum_{e->n} esc_e*comp2[r_e,b]*h[src_e,i] )
// ---------------------------------------------------------------------------
__global__ __launch_bounds__(256) void agg2e_kernel(
    const unsigned short* __restrict__ hb, const int* __restrict__ off,
    const int* __restrict__ rec, const float* __restrict__ esc,
    const float* __restrict__ comp, unsigned short* __restrict__ A2b) {
  __shared__ float s_comp[RR * 8];
  const int tid = threadIdx.x;
  for (int i = tid; i < RR * 8; i += 256) s_comp[i] = comp[i];
  __syncthreads();
  const int wv = tid >> 6, lane = tid & 63;
  const int n = blockIdx.x * 4 + wv;
  if (n >= NN) return;
  float acc[8];
#pragma unroll
  for (int b = 0; b < 8; b++) acc[b] = 0.f;
  const int beg = off[n], end = off[n + 1];
  int idx = beg;
  for (; idx + 3 < end; idx += 4) {
    int rc[4]; float sc[4]; float hv[4];
#pragma unroll
    for (int u = 0; u < 4; u++) {
      rc[u] = rec[idx + u];
      sc[u] = esc[idx + u];
    }
#pragma unroll
    for (int u = 0; u < 4; u++)
      hv[u] = bf2f(hb[(size_t)(rc[u] & 16383) * D2 + lane]);
#pragma unroll
    for (int u = 0; u < 4; u++) {
      const float* cb = &s_comp[(rc[u] >> 14) * 8];
#pragma unroll
      for (int b = 0; b < 8; b++) acc[b] += sc[u] * cb[b] * hv[u];
    }
  }
  for (; idx < end; idx++) {
    int rc = rec[idx];
    float sc = esc[idx];
    float hv = bf2f(hb[(size_t)(rc & 16383) * D2 + lane]);
    const float* cb = &s_comp[(rc >> 14) * 8];
#pragma unroll
    for (int b = 0; b < 8; b++) acc[b] += sc * cb[b] * hv;
  }
#pragma unroll
  for (int b = 0; b < 8; b++)
    A2b[(size_t)n * 512 + b * 64 + lane] = f2bf(acc[b]);
}

// ---------------------------------------------------------------------------
// hlayer: hb = bf16(relu([xb|A1b](K=1152) @ Wc1T + bias1))
// MFMA, tile M=32 x N=64 (313 blocks), register-prefetch pipeline
// ---------------------------------------------------------------------------
__global__ __launch_bounds__(256) void hlayer_mfma(
    const unsigned short* __restrict__ xb, const unsigned short* __restrict__ A1b,
    const unsigned short* __restrict__ Wt, const float* __restrict__ bias1,
    unsigned short* __restrict__ hb) {
  __shared__ unsigned short Asb[32][40];
  __shared__ unsigned short Bsb[64][40];
  const int tid = threadIdx.x;
  const int m0 = blockIdx.x * 32;
  const int wv = tid >> 6, lane = tid & 63;
  const int lrow = lane & 15, quad = lane >> 4;
  const int mt = wv >> 1, ntb = (wv & 1) * 2;

  const int brow = tid >> 2, bq = tid & 3;          // B: 64 rows
  const int as_row = (tid & 127) >> 2;              // A: 32 rows (tid<128)
  int gr = m0 + as_row; if (gr >= NN) gr = NN - 1;
  const unsigned short* Arow_x = &xb[(size_t)gr * D1 + bq * 8];
  const unsigned short* Arow_a = &A1b[(size_t)gr * 1024 + bq * 8];
  const unsigned short* Bp = &Wt[(size_t)brow * 1152 + bq * 8];

  uint4 ra0, ra1, rb0, rb1;

#define H_LOAD(ra, rb, c)                                                    \
  { int kb = (c) * 32;                                                       \
    if (tid < 128)                                                           \
      ra = (kb < 128) ? *(const uint4*)(Arow_x + kb)                         \
                      : *(const uint4*)(Arow_a + (kb - 128));                \
    rb = *(const uint4*)(Bp + kb); }

#define H_STORE(ra, rb)                                                      \
  { if (tid < 128) *(uint4*)&Asb[as_row][bq * 8] = ra;                       \
    *(uint4*)&Bsb[brow][bq * 8] = rb; }

#define H_COMPUTE()                                                          \
  { short8 af = *(const short8*)&Asb[mt * 16 + lrow][quad * 8];              \
    _Pragma("unroll")                                                        \
    for (int ntl = 0; ntl < 2; ntl++) {                                      \
      short8 bfr = *(const short8*)&Bsb[(ntb + ntl) * 16 + lrow][quad * 8];  \
      acc[ntl] = __builtin_amdgcn_mfma_f32_16x16x32_bf16(af, bfr, acc[ntl], 0, 0, 0); \
    } }

  float4e acc[2];
#pragma unroll
  for (int i = 0; i < 2; i++) { acc[i][0]=0.f; acc[i][1]=0.f; acc[i][2]=0.f; acc[i][3]=0.f; }

  H_LOAD(ra0, rb0, 0);
  for (int c = 0; c < 36; c += 2) {
    H_STORE(ra0, rb0);
    __syncthreads();
    if (c + 1 < 36) H_LOAD(ra1, rb1, c + 1);
    H_COMPUTE();
    __syncthreads();
    H_STORE(ra1, rb1);
    __syncthreads();
    if (c + 2 < 36) H_LOAD(ra0, rb0, c + 2);
    H_COMPUTE();
    __syncthreads();
  }

#pragma unroll
  for (int ntl = 0; ntl < 2; ntl++) {
    int col = (ntb + ntl) * 16 + lrow;
    float bv = bias1[col];
#pragma unroll
    for (int r = 0; r < 4; r++) {
      int row = m0 + mt * 16 + quad * 4 + r;
      if (row < NN)
        hb[(size_t)row * D2 + col] = f2bf(fmaxf(acc[ntl][r] + bv, 0.f));
    }
  }
}

// ---------------------------------------------------------------------------
// out: out = [hb|A2b](K=576) @ Wc2T + bias2
// MFMA, tile M=32 x N=32 (313 blocks), register-prefetch pipeline
// ---------------------------------------------------------------------------
__global__ __launch_bounds__(256) void out_mfma(
    const unsigned short* __restrict__ hb, const unsigned short* __restrict__ A2b,
    const unsigned short* __restrict__ Wt, const float* __restrict__ bias2,
    float* __restrict__ out) {
  __shared__ unsigned short Asb[32][40];
  __shared__ unsigned short Bsb[32][40];
  const int tid = threadIdx.x;
  const int m0 = blockIdx.x * 32;
  const int wv = tid >> 6, lane = tid & 63;
  const int lrow = lane & 15, quad = lane >> 4;
  const int mt = wv >> 1, nt = wv & 1;

  const int srow = (tid & 127) >> 2, sq = tid & 3;  // 32 rows per half
  int gr = m0 + srow; if (gr >= NN) gr = NN - 1;
  const unsigned short* Arow_h = &hb[(size_t)gr * D2 + sq * 8];
  const unsigned short* Arow_a = &A2b[(size_t)gr * 512 + sq * 8];
  const unsigned short* Bp = &Wt[(size_t)srow * 576 + sq * 8];

  uint4 r0, r1;

#define O_LOAD(rg, c)                                                        \
  { int kb = (c) * 32;                                                       \
    if (tid < 128)                                                           \
      rg = (kb < 64) ? *(const uint4*)(Arow_h + kb)                          \
                     : *(const uint4*)(Arow_a + (kb - 64));                  \
    else                                                                     \
      rg = *(const uint4*)(Bp + kb); }

#define O_STORE(rg)                                                          \
  { if (tid < 128) *(uint4*)&Asb[srow][sq * 8] = rg;                         \
    else           *(uint4*)&Bsb[srow][sq * 8] = rg; }

#define O_COMPUTE()                                                          \
  { short8 af = *(const short8*)&Asb[mt * 16 + lrow][quad * 8];              \
    short8 bfr = *(const short8*)&Bsb[nt * 16 + lrow][quad * 8];             \
    acc = __builtin_amdgcn_mfma_f32_16x16x32_bf16(af, bfr, acc, 0, 0, 0); }

  float4e acc;
  acc[0]=0.f; acc[1]=0.f; acc[2]=0.f; acc[3]=0.f;

  O_LOAD(r0, 0);
  for (int c = 0; c < 18; c += 2) {
    O_STORE(r0);
    __syncthreads();
    if (c + 1 < 18) O_LOAD(r1, c + 1);
    O_COMPUTE();
    __syncthreads();
    O_STORE(r1);
    __syncthreads();
    if (c + 2 < 18) O_LOAD(r0, c + 2);
    O_COMPUTE();
    __syncthreads();
  }

  int col = nt * 16 + lrow;
  if (col < D3) {
    float bv = bias2[col];
#pragma unroll
    for (int r = 0; r < 4; r++) {
      int row = m0 + mt * 16 + quad * 4 + r;
      if (row < NN)
        out[(size_t)row * D3 + col] = acc[r] + bv;
    }
  }
}

// ---------------------------------------------------------------------------
extern "C" void kernel_launch(void* const* d_in, const int* in_sizes, int n_in,
                              void* d_out, int out_size, void* d_ws,
                              size_t ws_size, hipStream_t stream) {
  const float* x_drug = (const float*)d_in[0];
  const float* drug_w = (const float*)d_in[1];
  const int*   ei     = (const int*)d_in[2];
  const float* basis1 = (const float*)d_in[3];
  const float* comp1  = (const float*)d_in[4];
  const float* root1  = (const float*)d_in[5];
  const float* bias1  = (const float*)d_in[6];
  const float* basis2 = (const float*)d_in[7];
  const float* comp2  = (const float*)d_in[8];
  const float* root2  = (const float*)d_in[9];
  const float* bias2  = (const float*)d_in[10];
  float* out = (float*)d_out;

  float* ws = (float*)d_ws;
  int*   deg  = (int*)ws;                          // 1,000,000
  int*   cnt  = deg + 1000000;                     // 10,016
  int*   off  = cnt + 10016;                       // 10,016
  int*   cur  = off + 10016;                       // 10,016
  int*   rec  = cur + 10016;                       // 500,000
  float* esc  = (float*)(rec + 500000);            // 500,000
  unsigned short* xb   = (unsigned short*)(esc + 500000);          // 640,000 f
  unsigned short* hb   = (unsigned short*)((float*)xb + 640000);   // 320,000 f
  unsigned short* Btw  = (unsigned short*)((float*)hb + 320000);   // 131,072 f
  unsigned short* Wc1T = (unsigned short*)((float*)Btw + 131072);  // 36,864 f
  unsigned short* Wc2T = (unsigned short*)((float*)Wc1T + 36864);  // 9,216 f
  float* R1 = (float*)Wc2T + 9216;                 // 5,120,000 floats shared
  float* xp = R1;                                  // 4 x 1,280,000 fp32 partials
  unsigned short* A1b = (unsigned short*)R1;       // aliases xp (after reduce)
  unsigned short* A2b = (unsigned short*)R1;       // aliases A1b (after hlayer)

  hipMemsetAsync(deg, 0, (size_t)1000000 * 4, stream);

  // CSR build
  deg_kernel<<<(NE + 255) / 256, 256, 0, stream>>>(ei, deg);
  cnt_kernel<<<(NN + 255) / 256, 256, 0, stream>>>(deg, cnt);
  scan_kernel<<<1, 1024, 0, stream>>>(cnt, off, cur);
  scatter_kernel<<<(NE + 255) / 256, 256, 0, stream>>>(ei, deg, cur, rec, esc);

  // weights
  wtrans_kernel<<<(128 * 2048 + 255) / 256, 256, 0, stream>>>(drug_w, Btw);
  wc1t_kernel<<<(64 * 1152 + 255) / 256, 256, 0, stream>>>(root1, basis1, Wc1T);
  wc2t_kernel<<<(32 * 576 + 255) / 256, 256, 0, stream>>>(root2, basis2, Wc2T);

  // x = x_drug @ drug_w (bf16 MFMA, K-split 4 + reduce)
  gemm0_mfma<<<dim3(157, 4), 256, 0, stream>>>(x_drug, Btw, xp);
  reduce_kernel<<<(NN * D1 / 4 + 255) / 256, 256, 0, stream>>>(xp, xb);

  // layer 1
  agg1e_kernel<<<(NN + 3) / 4, 256, 0, stream>>>(xb, off, rec, esc, comp1, A1b);
  hlayer_mfma<<<(NN + 31) / 32, 256, 0, stream>>>(xb, A1b, Wc1T, bias1, hb);

  // layer 2
  agg2e_kernel<<<(NN + 3) / 4, 256, 0, stream>>>(hb, off, rec, esc, comp2, A2b);
  out_mfma<<<(NN + 31) / 32, 256, 0, stream>>>(hb, A2b, Wc2T, bias2, out);
}